// Round 1
// baseline (221.768 us; speedup 1.0000x reference)
//
#include <hip/hip_runtime.h>
#include <stdint.h>

typedef unsigned short u16;
typedef __attribute__((ext_vector_type(8))) short bf16x8;
typedef __attribute__((ext_vector_type(4))) float f32x4;

#define DEVI static __device__ __forceinline__

static constexpr int NTOK = 2048;   // N tokens (= T*H*W = 8*16*16)
static constexpr int CDIM = 1024;
static constexpr int C3   = 3072;

// ---------- helpers ----------
DEVI u16 f2bf(float f) {            // f32 -> bf16 bits, RNE
  uint32_t u = __float_as_uint(f);
  return (u16)((u + 0x7fffu + ((u >> 16) & 1u)) >> 16);
}

DEVI void gl_lds16(const void* g, void* l) {  // 16B/lane global->LDS DMA
  __builtin_amdgcn_global_load_lds(
      (__attribute__((address_space(1))) uint32_t*)g,
      (__attribute__((address_space(3))) uint32_t*)l, 16, 0, 0);
}

DEVI f32x4 mfma16(bf16x8 a, bf16x8 b, f32x4 c) {
  return __builtin_amdgcn_mfma_f32_16x16x32_bf16(a, b, c, 0, 0, 0);
}

// ---------- f32 -> bf16 convert ----------
__global__ void k_cvt(const float* __restrict__ in, u16* __restrict__ out, int n) {
  int i = (blockIdx.x * blockDim.x + threadIdx.x) * 4;
  if (i >= n) return;
  float4 v = *reinterpret_cast<const float4*>(in + i);
  ushort4 o;
  o.x = f2bf(v.x); o.y = f2bf(v.y); o.z = f2bf(v.z); o.w = f2bf(v.w);
  *reinterpret_cast<ushort4*>(out + i) = o;
}

// ---------- bf16 GEMM: C[m][n] = sum_k A[m][k]*B[n][k] (+bias[n]) ----------
// 128x128 tile, BK=32, 4 waves (2x2 of 64x64), m97 structure.
template<bool BIAS>
__global__ __launch_bounds__(256, 2) void k_gemm(
    const u16* __restrict__ A, const u16* __restrict__ Bw,
    float* __restrict__ Cout, const float* __restrict__ bias,
    int Nn, int K) {
  __shared__ u16 Al[128 * 32];
  __shared__ u16 Bl[128 * 32];
  const int tid = threadIdx.x, wid = tid >> 6, lane = tid & 63;
  const int bm = blockIdx.x, bn = blockIdx.y;
  const int wr = wid >> 1, wc = wid & 1;
  f32x4 acc[4][4] = {};

  const int r0 = wid * 16 + (lane >> 2);   // staging row within 64-row shot
  const int c0 = (lane & 3) * 8;           // staging k-offset (elems)
  const u16* Ag = A + (size_t)(bm * 128) * K + c0;
  const u16* Bg = Bw + (size_t)(bn * 128) * K + c0;
  u16* Alb = Al + wid * 512;               // wave-uniform LDS dst (bytes wid*1024)
  u16* Blb = Bl + wid * 512;
  const int fr = lane & 15, fk = (lane >> 4) * 8;

  for (int kt = 0; kt < K; kt += 32) {
    __syncthreads();
    gl_lds16(Ag + (size_t)r0 * K + kt,        Alb);
    gl_lds16(Ag + (size_t)(64 + r0) * K + kt, Alb + 2048);
    gl_lds16(Bg + (size_t)r0 * K + kt,        Blb);
    gl_lds16(Bg + (size_t)(64 + r0) * K + kt, Blb + 2048);
    __syncthreads();
    bf16x8 af[4], bfr[4];
#pragma unroll
    for (int i = 0; i < 4; ++i)
      af[i] = *reinterpret_cast<const bf16x8*>(&Al[(wr * 64 + i * 16 + fr) * 32 + fk]);
#pragma unroll
    for (int j = 0; j < 4; ++j)
      bfr[j] = *reinterpret_cast<const bf16x8*>(&Bl[(wc * 64 + j * 16 + fr) * 32 + fk]);
#pragma unroll
    for (int i = 0; i < 4; ++i)
#pragma unroll
      for (int j = 0; j < 4; ++j)
        acc[i][j] = mfma16(af[i], bfr[j], acc[i][j]);
  }
  // epilogue: D row=(lane>>4)*4+r (M), col=lane&15 (N)  [m89-verified]
  const int orow0 = bm * 128 + wr * 64 + (lane >> 4) * 4;
  const int ocol0 = bn * 128 + wc * 64 + (lane & 15);
#pragma unroll
  for (int j = 0; j < 4; ++j) {
    int col = ocol0 + j * 16;
    float badd = BIAS ? bias[col] : 0.f;
#pragma unroll
    for (int i = 0; i < 4; ++i)
#pragma unroll
      for (int r = 0; r < 4; ++r)
        Cout[(size_t)(orow0 + i * 16 + r) * Nn + col] = acc[i][j][r] + badd;
  }
}

// ---------- RoPE on q,k (f32 in, bf16 out; q pre-scaled by hd^-0.5) ----------
// qkv layout [m=b*2048+n][o], o = which*1024 + h*64 + d. Out: [b][h][n][d].
__global__ void k_rope(const float* __restrict__ qkv,
                       u16* __restrict__ qb, u16* __restrict__ kb) {
  int flat = blockIdx.x * blockDim.x + threadIdx.x;   // over 2*16*2048*64
  int d = flat & 63;
  int n = (flat >> 6) & (NTOK - 1);
  int h = (flat >> 17) & 15;
  int b = flat >> 21;
  size_t m = (size_t)b * NTOK + n;
  const float* row = qkv + m * C3;
  int o = h * 64 + d;
  float qv = row[o], kv = row[CDIM + o];
  float qo, ko;
  if (d < 60) {
    int seg = d / 20;
    int ds = d - seg * 20;
    int j = ds % 10;
    float pos;
    if (seg == 0)      pos = (float)(n >> 8);          // id/(H*W)
    else if (seg == 1) pos = (float)((n >> 4) & 15);   // (rem/W)*(16/H)
    else               pos = (float)(n & 15);          // (rem%W)*(16/W)
    float omega = __powf(10000.f, -(float)j * 0.1f);
    float f = pos * omega;
    float sn, cs;
    __sincosf(f, &sn, &cs);
    float qp = row[o ^ 1], kp = row[CDIM + (o ^ 1)];   // pair partner
    if (d & 1) { qo = qv * cs + qp * sn; ko = kv * cs + kp * sn; }
    else       { qo = qv * cs - qp * sn; ko = kv * cs - kp * sn; }
  } else { qo = qv; ko = kv; }
  qb[flat] = f2bf(qo * 0.125f);   // fold softmax scale into q
  kb[flat] = f2bf(ko);
}

// ---------- V transpose: qkv v-part [n][d] f32 -> vT [b][h][d][n] bf16 ----------
__global__ void k_vt(const float* __restrict__ qkv, u16* __restrict__ vT) {
  __shared__ u16 tile[64][68];
  const int bh = blockIdx.x;           // b*16+h
  const int n0 = blockIdx.y * 64;
  const int b = bh >> 4, h = bh & 15;
  const int t = threadIdx.x;
  const int nr = t >> 2, cq = (t & 3) * 16;
  const float* src = qkv + ((size_t)b * NTOK + n0 + nr) * C3 + 2 * CDIM + h * 64 + cq;
#pragma unroll
  for (int i = 0; i < 16; i += 4) {
    float4 v = *reinterpret_cast<const float4*>(src + i);
    tile[nr][cq + i + 0] = f2bf(v.x);
    tile[nr][cq + i + 1] = f2bf(v.y);
    tile[nr][cq + i + 2] = f2bf(v.z);
    tile[nr][cq + i + 3] = f2bf(v.w);
  }
  __syncthreads();
  const int d = t >> 2, nq = (t & 3) * 16;
  u16* dst = vT + ((size_t)bh * 64 + d) * NTOK + n0 + nq;
#pragma unroll
  for (int i = 0; i < 16; ++i) dst[i] = tile[nq + i][d];
}

// ---------- flash attention ----------
// block = 4 waves; wave w owns q-rows [qt*64 + w*16, +16); KV stepped by 32.
// S^T = mfma(K,Q): lane holds S^T[kv=mf*16+(lane>>4)*4+r][q=lane&15].
__global__ __launch_bounds__(256, 2) void k_attn(
    const u16* __restrict__ qb, const u16* __restrict__ kb,
    const u16* __restrict__ vT, u16* __restrict__ outb) {
  __shared__ u16 Kl[32 * 64];      // [kv][d]
  __shared__ u16 Vl[64 * 32];      // [d][kv]  (from vT)
  __shared__ u16 Pl[4][16 * 32];   // per-wave P [q][kv]
  const int bh = blockIdx.x;       // b*16+h
  const int qt = blockIdx.y;       // q-tile (64 rows)
  const int tid = threadIdx.x, wid = tid >> 6, lane = tid & 63;
  const int fr = lane & 15, fg = lane >> 4;

  const u16* qrow = qb + ((size_t)bh * NTOK + qt * 64 + wid * 16 + fr) * 64;
  bf16x8 qf0 = *reinterpret_cast<const bf16x8*>(qrow + fg * 8);
  bf16x8 qf1 = *reinterpret_cast<const bf16x8*>(qrow + 32 + fg * 8);

  f32x4 acc[4] = {};
  float mrun = -1e30f, lrun = 0.f;

  const int krow = wid * 8 + (lane >> 3), kcol = (lane & 7) * 8;
  const u16* kg = kb + ((size_t)bh * NTOK + krow) * 64 + kcol;
  const int vrow = wid * 16 + (lane >> 2), vcol = (lane & 3) * 8;
  const u16* vg = vT + ((size_t)bh * 64 + vrow) * NTOK + vcol;
  u16* Pw = &Pl[wid][0];

  for (int kvt = 0; kvt < NTOK; kvt += 32) {
    __syncthreads();
    gl_lds16(kg + (size_t)kvt * 64, Kl + wid * 512);
    gl_lds16(vg + kvt,              Vl + wid * 512);
    __syncthreads();

    f32x4 st[2] = {};
#pragma unroll
    for (int mf = 0; mf < 2; ++mf) {
      bf16x8 kf0 = *reinterpret_cast<const bf16x8*>(&Kl[(mf * 16 + fr) * 64 + fg * 8]);
      bf16x8 kf1 = *reinterpret_cast<const bf16x8*>(&Kl[(mf * 16 + fr) * 64 + 32 + fg * 8]);
      st[mf] = mfma16(kf0, qf0, st[mf]);
      st[mf] = mfma16(kf1, qf1, st[mf]);
    }
    // online softmax stats for q = fr (replicated over the 4 fg-groups)
    float tm = -1e30f;
#pragma unroll
    for (int mf = 0; mf < 2; ++mf)
#pragma unroll
      for (int r = 0; r < 4; ++r) tm = fmaxf(tm, st[mf][r]);
    tm = fmaxf(tm, __shfl_xor(tm, 16, 64));
    tm = fmaxf(tm, __shfl_xor(tm, 32, 64));
    float mnew = fmaxf(mrun, tm);
    float corr = __expf(mrun - mnew);
    mrun = mnew;
    float ps = 0.f;
    u16 pb[8];
#pragma unroll
    for (int mf = 0; mf < 2; ++mf)
#pragma unroll
      for (int r = 0; r < 4; ++r) {
        float p = __expf(st[mf][r] - mnew);
        ps += p;
        pb[mf * 4 + r] = f2bf(p);
      }
    ps += __shfl_xor(ps, 16, 64);
    ps += __shfl_xor(ps, 32, 64);
    lrun = lrun * corr + ps;
    // P -> LDS [q][kv] so PV can read proper A-fragments
#pragma unroll
    for (int mf = 0; mf < 2; ++mf)
#pragma unroll
      for (int r = 0; r < 4; ++r)
        Pw[fr * 32 + mf * 16 + fg * 4 + r] = pb[mf * 4 + r];
    asm volatile("" ::: "memory");   // keep ds_writes before ds_read (in-order per wave)
    // rescale accumulator rows q' = fg*4+r
    float corr_r[4];
#pragma unroll
    for (int r = 0; r < 4; ++r) corr_r[r] = __shfl(corr, fg * 4 + r, 64);
#pragma unroll
    for (int nf = 0; nf < 4; ++nf)
#pragma unroll
      for (int r = 0; r < 4; ++r) acc[nf][r] *= corr_r[r];
    // PV: out[q][d] += P[q][kv] * V^T[d][kv]
    bf16x8 pa = *reinterpret_cast<const bf16x8*>(&Pw[fr * 32 + fg * 8]);
#pragma unroll
    for (int nf = 0; nf < 4; ++nf) {
      bf16x8 vf = *reinterpret_cast<const bf16x8*>(&Vl[(nf * 16 + fr) * 32 + fg * 8]);
      acc[nf] = mfma16(pa, vf, acc[nf]);
    }
  }
  // normalize + write [b][n][h*64+d] bf16
  float linv[4];
#pragma unroll
  for (int r = 0; r < 4; ++r) linv[r] = 1.f / __shfl(lrun, fg * 4 + r, 64);
  const int b = bh >> 4, h = bh & 15;
#pragma unroll
  for (int nf = 0; nf < 4; ++nf)
#pragma unroll
    for (int r = 0; r < 4; ++r) {
      int n = qt * 64 + wid * 16 + fg * 4 + r;
      int col = h * 64 + nf * 16 + fr;
      outb[((size_t)b * NTOK + n) * CDIM + col] = f2bf(acc[nf][r] * linv[r]);
    }
}

// ---------- launcher ----------
extern "C" void kernel_launch(void* const* d_in, const int* in_sizes, int n_in,
                              void* d_out, int out_size, void* d_ws, size_t ws_size,
                              hipStream_t stream) {
  (void)in_sizes; (void)n_in; (void)out_size; (void)ws_size;
  const float* x  = (const float*)d_in[0];
  const float* Wq = (const float*)d_in[1];
  const float* Wp = (const float*)d_in[2];
  const float* bp = (const float*)d_in[3];
  // T=8, H=16, W=16 fixed (d_in[4..6]); N = 2048 = T*H*W.

  char* w = (char*)d_ws;
  u16*   x_bf  = (u16*)  (w + 0);          //  8,388,608 B
  u16*   wq_bf = (u16*)  (w + 8388608);    //  6,291,456
  u16*   wp_bf = (u16*)  (w + 14680064);   //  2,097,152
  float* qkv   = (float*)(w + 16777216);   // 50,331,648
  u16*   q_bf  = (u16*)  (w + 67108864);   //  8,388,608
  u16*   k_bf  = (u16*)  (w + 75497472);   //  8,388,608
  u16*   vT    = (u16*)  (w + 83886080);   //  8,388,608
  u16*   at_bf = (u16*)  (w + 92274688);   //  8,388,608  (total ~96 MB)

  k_cvt<<<4096, 256, 0, stream>>>(x,  x_bf,  4194304);
  k_cvt<<<3072, 256, 0, stream>>>(Wq, wq_bf, 3145728);
  k_cvt<<<1024, 256, 0, stream>>>(Wp, wp_bf, 1048576);

  k_gemm<false><<<dim3(32, 24), 256, 0, stream>>>(x_bf, wq_bf, qkv, nullptr, C3, CDIM);

  k_rope<<<16384, 256, 0, stream>>>(qkv, q_bf, k_bf);
  k_vt<<<dim3(32, 32), 256, 0, stream>>>(qkv, vT);

  k_attn<<<dim3(32, 32), 256, 0, stream>>>(q_bf, k_bf, vT, at_bf);

  k_gemm<true><<<dim3(32, 8), 256, 0, stream>>>(at_bf, wp_bf, (float*)d_out, bp, CDIM, CDIM);
}

// Round 3
// 160.200 us; speedup vs baseline: 1.3843x; 1.3843x over previous
//
#include <hip/hip_runtime.h>
#include <stdint.h>

typedef unsigned short u16;
typedef __attribute__((ext_vector_type(8))) short bf16x8;
typedef __attribute__((ext_vector_type(4))) float f32x4;

#define DEVI static __device__ __forceinline__

static constexpr int NTOK = 2048;   // N tokens (= T*H*W = 8*16*16)
static constexpr int CDIM = 1024;
static constexpr int C3   = 3072;

// ---------- helpers ----------
DEVI u16 f2bf(float f) {            // f32 -> bf16 bits, RNE
  uint32_t u = __float_as_uint(f);
  return (u16)((u + 0x7fffu + ((u >> 16) & 1u)) >> 16);
}

DEVI float exp2fast(float x) { return __builtin_amdgcn_exp2f(x); }  // v_exp_f32 (base 2)

DEVI void gl_lds16(const void* g, void* l) {  // 16B/lane global->LDS DMA
  __builtin_amdgcn_global_load_lds(
      (__attribute__((address_space(1))) uint32_t*)g,
      (__attribute__((address_space(3))) uint32_t*)l, 16, 0, 0);
}

DEVI f32x4 mfma16(bf16x8 a, bf16x8 b, f32x4 c) {
  return __builtin_amdgcn_mfma_f32_16x16x32_bf16(a, b, c, 0, 0, 0);
}

// ---------- f32 -> bf16 convert ----------
__global__ void k_cvt(const float* __restrict__ in, u16* __restrict__ out, int n) {
  int i = (blockIdx.x * blockDim.x + threadIdx.x) * 4;
  if (i >= n) return;
  float4 v = *reinterpret_cast<const float4*>(in + i);
  ushort4 o;
  o.x = f2bf(v.x); o.y = f2bf(v.y); o.z = f2bf(v.z); o.w = f2bf(v.w);
  *reinterpret_cast<ushort4*>(out + i) = o;
}

// ---------- bf16 GEMM: C[m][n] = sum_k A[m][k]*B[n][k] (+bias[n]) ----------
// 128x128 tile, BK=32, 4 waves (2x2 of 64x64), m97 structure.
template<bool BIAS>
__global__ __launch_bounds__(256, 2) void k_gemm(
    const u16* __restrict__ A, const u16* __restrict__ Bw,
    float* __restrict__ Cout, const float* __restrict__ bias,
    int Nn, int K) {
  __shared__ u16 Al[128 * 32];
  __shared__ u16 Bl[128 * 32];
  const int tid = threadIdx.x, wid = tid >> 6, lane = tid & 63;
  const int bm = blockIdx.x, bn = blockIdx.y;
  const int wr = wid >> 1, wc = wid & 1;
  f32x4 acc[4][4] = {};

  const int r0 = wid * 16 + (lane >> 2);   // staging row within 64-row shot
  const int c0 = (lane & 3) * 8;           // staging k-offset (elems)
  const u16* Ag = A + (size_t)(bm * 128) * K + c0;
  const u16* Bg = Bw + (size_t)(bn * 128) * K + c0;
  u16* Alb = Al + wid * 512;               // wave-uniform LDS dst (bytes wid*1024)
  u16* Blb = Bl + wid * 512;
  const int fr = lane & 15, fk = (lane >> 4) * 8;

  for (int kt = 0; kt < K; kt += 32) {
    __syncthreads();
    gl_lds16(Ag + (size_t)r0 * K + kt,        Alb);
    gl_lds16(Ag + (size_t)(64 + r0) * K + kt, Alb + 2048);
    gl_lds16(Bg + (size_t)r0 * K + kt,        Blb);
    gl_lds16(Bg + (size_t)(64 + r0) * K + kt, Blb + 2048);
    __syncthreads();
    bf16x8 af[4], bfr[4];
#pragma unroll
    for (int i = 0; i < 4; ++i)
      af[i] = *reinterpret_cast<const bf16x8*>(&Al[(wr * 64 + i * 16 + fr) * 32 + fk]);
#pragma unroll
    for (int j = 0; j < 4; ++j)
      bfr[j] = *reinterpret_cast<const bf16x8*>(&Bl[(wc * 64 + j * 16 + fr) * 32 + fk]);
#pragma unroll
    for (int i = 0; i < 4; ++i)
#pragma unroll
      for (int j = 0; j < 4; ++j)
        acc[i][j] = mfma16(af[i], bfr[j], acc[i][j]);
  }
  // epilogue: D row=(lane>>4)*4+r (M), col=lane&15 (N)  [m89-verified]
  const int orow0 = bm * 128 + wr * 64 + (lane >> 4) * 4;
  const int ocol0 = bn * 128 + wc * 64 + (lane & 15);
#pragma unroll
  for (int j = 0; j < 4; ++j) {
    int col = ocol0 + j * 16;
    float badd = BIAS ? bias[col] : 0.f;
#pragma unroll
    for (int i = 0; i < 4; ++i)
#pragma unroll
      for (int r = 0; r < 4; ++r)
        Cout[(size_t)(orow0 + i * 16 + r) * Nn + col] = acc[i][j][r] + badd;
  }
}

// ---------- RoPE on q,k (f32 in, bf16 out) ----------
// q pre-scaled by hd^-0.5 * log2(e) so attention softmax can use exp2.
// qkv layout [m=b*2048+n][o], o = which*1024 + h*64 + d. Out: [b][h][n][d].
__global__ void k_rope(const float* __restrict__ qkv,
                       u16* __restrict__ qb, u16* __restrict__ kb) {
  int flat = blockIdx.x * blockDim.x + threadIdx.x;   // over 2*16*2048*64
  int d = flat & 63;
  int n = (flat >> 6) & (NTOK - 1);
  int h = (flat >> 17) & 15;
  int b = flat >> 21;
  size_t m = (size_t)b * NTOK + n;
  const float* row = qkv + m * C3;
  int o = h * 64 + d;
  float qv = row[o], kv = row[CDIM + o];
  float qo, ko;
  if (d < 60) {
    int seg = d / 20;
    int ds = d - seg * 20;
    int j = ds % 10;
    float pos;
    if (seg == 0)      pos = (float)(n >> 8);          // id/(H*W)
    else if (seg == 1) pos = (float)((n >> 4) & 15);   // (rem/W)*(16/H)
    else               pos = (float)(n & 15);          // (rem%W)*(16/W)
    float omega = __powf(10000.f, -(float)j * 0.1f);
    float f = pos * omega;
    float sn, cs;
    __sincosf(f, &sn, &cs);
    float qp = row[o ^ 1], kp = row[CDIM + (o ^ 1)];   // pair partner
    if (d & 1) { qo = qv * cs + qp * sn; ko = kv * cs + kp * sn; }
    else       { qo = qv * cs - qp * sn; ko = kv * cs - kp * sn; }
  } else { qo = qv; ko = kv; }
  qb[flat] = f2bf(qo * 0.18033688011112042f);   // 0.125 * log2(e)
  kb[flat] = f2bf(ko);
}

// ---------- V transpose: qkv v-part [n][d] f32 -> vT [b][h][d][n] bf16 ----------
__global__ void k_vt(const float* __restrict__ qkv, u16* __restrict__ vT) {
  __shared__ u16 tile[64][68];
  const int bh = blockIdx.x;           // b*16+h
  const int n0 = blockIdx.y * 64;
  const int b = bh >> 4, h = bh & 15;
  const int t = threadIdx.x;
  const int nr = t >> 2, cq = (t & 3) * 16;
  const float* src = qkv + ((size_t)b * NTOK + n0 + nr) * C3 + 2 * CDIM + h * 64 + cq;
#pragma unroll
  for (int i = 0; i < 16; i += 4) {
    float4 v = *reinterpret_cast<const float4*>(src + i);
    tile[nr][cq + i + 0] = f2bf(v.x);
    tile[nr][cq + i + 1] = f2bf(v.y);
    tile[nr][cq + i + 2] = f2bf(v.z);
    tile[nr][cq + i + 3] = f2bf(v.w);
  }
  __syncthreads();
  const int d = t >> 2, nq = (t & 3) * 16;
  u16* dst = vT + ((size_t)bh * 64 + d) * NTOK + n0 + nq;
#pragma unroll
  for (int i = 0; i < 16; ++i) dst[i] = tile[nq + i][d];
}

// ---------- flash attention ----------
// 4 waves/block; wave w owns 32 q-rows (2 x 16-row frags); KVBLK=64, dbuf LDS.
// All LDS tiles XOR-swizzled: 16B-chunk index ^= (row & 7). global_load_lds
// stays linear-dest; the GLOBAL source column is pre-swizzled (rule #21).
// S^T = mfma(K,Q): lane holds S^T[kv=mf*16+fg*4+r][q=fr], fg=lane>>4, fr=lane&15.
__global__ __launch_bounds__(256, 2) void k_attn(
    const u16* __restrict__ qb, const u16* __restrict__ kb,
    const u16* __restrict__ vT, u16* __restrict__ outb) {
  __shared__ u16 Kl[2][64 * 64];   // [kv][d]   rows 128B, swizzled
  __shared__ u16 Vl[2][64 * 64];   // [d][kv]   rows 128B, swizzled
  __shared__ u16 Pl[4][32 * 64];   // per-wave P [q][kv], rows 128B, swizzled
  const int bh = blockIdx.x;       // b*16+h
  const int qt = blockIdx.y;       // q-tile (128 rows)
  const int tid = threadIdx.x, wid = tid >> 6, lane = tid & 63;
  const int fr = lane & 15, fg = lane >> 4;
  const int swz = fr & 7;

  // Q fragments (held in registers for the whole kernel)
  bf16x8 qf[2][2];
  const u16* qbase = qb + ((size_t)bh * NTOK + qt * 128 + wid * 32 + fr) * 64;
#pragma unroll
  for (int qa = 0; qa < 2; ++qa)
#pragma unroll
    for (int h = 0; h < 2; ++h)
      qf[qa][h] = *reinterpret_cast<const bf16x8*>(qbase + qa * 1024 + h * 32 + fg * 8);

  f32x4 acc[2][4] = {};
  float mrun[2] = {-1e30f, -1e30f}, lrun[2] = {0.f, 0.f};

  // staging geometry: wave stages 8 rows (of 128B) per shot, 2 shots per tile
  const int srow = lane >> 3;                 // 0..7
  const int scol = ((lane & 7) ^ srow) * 8;   // pre-swizzled source col (elems)
  const u16* kg = kb + ((size_t)bh * NTOK + wid * 8 + srow) * 64 + scol;
  const u16* vg = vT + ((size_t)bh * 64 + wid * 8 + srow) * NTOK + scol;
  u16* Pw = &Pl[wid][0];

  auto stage = [&](int buf, int kvt) {
#pragma unroll
    for (int s = 0; s < 2; ++s) {
      gl_lds16(kg + (size_t)(kvt + s * 32) * 64, &Kl[buf][s * 2048 + wid * 512]);
      gl_lds16(vg + (size_t)(s * 32) * NTOK + kvt, &Vl[buf][s * 2048 + wid * 512]);
    }
  };

  stage(0, 0);
  __syncthreads();
  int cur = 0;
  for (int kvt = 0; kvt < NTOK; kvt += 64) {
    if (kvt + 64 < NTOK) stage(cur ^ 1, kvt + 64);
    const u16* Kc = &Kl[cur][0];
    const u16* Vc = &Vl[cur][0];

    bf16x8 kf[4][2], vf[4][2];
#pragma unroll
    for (int mf = 0; mf < 4; ++mf) {
      int rb = (mf * 16 + fr) * 64;
#pragma unroll
      for (int h = 0; h < 2; ++h)
        kf[mf][h] = *reinterpret_cast<const bf16x8*>(Kc + rb + (((h * 4 + fg) ^ swz) * 8));
    }
#pragma unroll
    for (int nf = 0; nf < 4; ++nf) {
      int rb = (nf * 16 + fr) * 64;
#pragma unroll
      for (int ks = 0; ks < 2; ++ks)
        vf[nf][ks] = *reinterpret_cast<const bf16x8*>(Vc + rb + (((ks * 4 + fg) ^ swz) * 8));
    }

    // QK^T (K frags reused across both q-frags)
    f32x4 st[2][4];
#pragma unroll
    for (int qa = 0; qa < 2; ++qa)
#pragma unroll
      for (int mf = 0; mf < 4; ++mf) {
        f32x4 s0 = {};
        s0 = mfma16(kf[mf][0], qf[qa][0], s0);
        s0 = mfma16(kf[mf][1], qf[qa][1], s0);
        st[qa][mf] = s0;
      }

    // online softmax (log2 domain; scale folded into q)
    float corrA[2];
#pragma unroll
    for (int qa = 0; qa < 2; ++qa) {
      float tm = -1e30f;
#pragma unroll
      for (int mf = 0; mf < 4; ++mf)
#pragma unroll
        for (int r = 0; r < 4; ++r) tm = fmaxf(tm, st[qa][mf][r]);
      tm = fmaxf(tm, __shfl_xor(tm, 16, 64));
      tm = fmaxf(tm, __shfl_xor(tm, 32, 64));
      float mnew = fmaxf(mrun[qa], tm);
      corrA[qa] = exp2fast(mrun[qa] - mnew);
      mrun[qa] = mnew;
      float ps = 0.f;
      const int prow = qa * 16 + fr;
#pragma unroll
      for (int mf = 0; mf < 4; ++mf) {
        float p0 = exp2fast(st[qa][mf][0] - mnew);
        float p1 = exp2fast(st[qa][mf][1] - mnew);
        float p2 = exp2fast(st[qa][mf][2] - mnew);
        float p3 = exp2fast(st[qa][mf][3] - mnew);
        ps += (p0 + p1) + (p2 + p3);
        uint32_t k0, k1;
        asm("v_cvt_pk_bf16_f32 %0, %1, %2" : "=v"(k0) : "v"(p0), "v"(p1));
        asm("v_cvt_pk_bf16_f32 %0, %1, %2" : "=v"(k1) : "v"(p2), "v"(p3));
        int c16 = (mf * 2 + (fg >> 1)) ^ swz;
        uint2 val; val.x = k0; val.y = k1;
        *reinterpret_cast<uint2*>(Pw + prow * 64 + c16 * 8 + (fg & 1) * 4) = val;
      }
      ps += __shfl_xor(ps, 16, 64);
      ps += __shfl_xor(ps, 32, 64);
      lrun[qa] = lrun[qa] * corrA[qa] + ps;
    }

    // rule-18 fence: P writes must land before P fragment re-read
    __builtin_amdgcn_sched_barrier(0);
    asm volatile("s_waitcnt lgkmcnt(0)" ::: "memory");
    __builtin_amdgcn_sched_barrier(0);

    // rescale + PV (V frags reused across both q-frags)
#pragma unroll
    for (int qa = 0; qa < 2; ++qa) {
      float cr[4];
#pragma unroll
      for (int r = 0; r < 4; ++r) cr[r] = __shfl(corrA[qa], fg * 4 + r, 64);
#pragma unroll
      for (int nf = 0; nf < 4; ++nf)
#pragma unroll
        for (int r = 0; r < 4; ++r) acc[qa][nf][r] *= cr[r];
      const int prow = qa * 16 + fr;
      bf16x8 pa[2];
#pragma unroll
      for (int ks = 0; ks < 2; ++ks)
        pa[ks] = *reinterpret_cast<const bf16x8*>(Pw + prow * 64 + (((ks * 4 + fg) ^ swz) * 8));
#pragma unroll
      for (int nf = 0; nf < 4; ++nf)
#pragma unroll
        for (int ks = 0; ks < 2; ++ks)
          acc[qa][nf] = mfma16(pa[ks], vf[nf][ks], acc[qa][nf]);
    }
    __syncthreads();
    cur ^= 1;
  }

  // normalize + write [b][n][h*64+d] bf16
  const int b = bh >> 4, h = bh & 15;
#pragma unroll
  for (int qa = 0; qa < 2; ++qa) {
    float linv[4];
#pragma unroll
    for (int r = 0; r < 4; ++r) linv[r] = 1.f / __shfl(lrun[qa], fg * 4 + r, 64);
#pragma unroll
    for (int nf = 0; nf < 4; ++nf)
#pragma unroll
      for (int r = 0; r < 4; ++r) {
        int n = qt * 128 + wid * 32 + qa * 16 + fg * 4 + r;
        int col = h * 64 + nf * 16 + fr;
        outb[((size_t)b * NTOK + n) * CDIM + col] = f2bf(acc[qa][nf][r] * linv[r]);
      }
  }
}

// ---------- launcher ----------
extern "C" void kernel_launch(void* const* d_in, const int* in_sizes, int n_in,
                              void* d_out, int out_size, void* d_ws, size_t ws_size,
                              hipStream_t stream) {
  (void)in_sizes; (void)n_in; (void)out_size; (void)ws_size;
  const float* x  = (const float*)d_in[0];
  const float* Wq = (const float*)d_in[1];
  const float* Wp = (const float*)d_in[2];
  const float* bp = (const float*)d_in[3];
  // T=8, H=16, W=16 fixed (d_in[4..6]); N = 2048 = T*H*W.

  char* w = (char*)d_ws;
  u16*   x_bf  = (u16*)  (w + 0);          //  8,388,608 B
  u16*   wq_bf = (u16*)  (w + 8388608);    //  6,291,456
  u16*   wp_bf = (u16*)  (w + 14680064);   //  2,097,152
  float* qkv   = (float*)(w + 16777216);   // 50,331,648
  u16*   q_bf  = (u16*)  (w + 67108864);   //  8,388,608
  u16*   k_bf  = (u16*)  (w + 75497472);   //  8,388,608
  u16*   vT    = (u16*)  (w + 83886080);   //  8,388,608
  u16*   at_bf = (u16*)  (w + 92274688);   //  8,388,608  (total ~96 MB)

  k_cvt<<<4096, 256, 0, stream>>>(x,  x_bf,  4194304);
  k_cvt<<<3072, 256, 0, stream>>>(Wq, wq_bf, 3145728);
  k_cvt<<<1024, 256, 0, stream>>>(Wp, wp_bf, 1048576);

  k_gemm<false><<<dim3(32, 24), 256, 0, stream>>>(x_bf, wq_bf, qkv, nullptr, C3, CDIM);

  k_rope<<<16384, 256, 0, stream>>>(qkv, q_bf, k_bf);
  k_vt<<<dim3(32, 32), 256, 0, stream>>>(qkv, vT);

  k_attn<<<dim3(32, 16), 256, 0, stream>>>(q_bf, k_bf, vT, at_bf);

  k_gemm<true><<<dim3(32, 8), 256, 0, stream>>>(at_bf, wp_bf, (float*)d_out, bp, CDIM, CDIM);
}

// Round 4
// 141.425 us; speedup vs baseline: 1.5681x; 1.1328x over previous
//
#include <hip/hip_runtime.h>
#include <stdint.h>

typedef unsigned short u16;
typedef __attribute__((ext_vector_type(8))) short bf16x8;
typedef __attribute__((ext_vector_type(4))) float f32x4;

#define DEVI static __device__ __forceinline__

static constexpr int NTOK = 2048;   // N tokens (= T*H*W = 8*16*16)
static constexpr int CDIM = 1024;
static constexpr int C3   = 3072;

// ---------- helpers ----------
DEVI u16 f2bf(float f) {            // f32 -> bf16 bits, RNE
  uint32_t u = __float_as_uint(f);
  return (u16)((u + 0x7fffu + ((u >> 16) & 1u)) >> 16);
}

DEVI float exp2fast(float x) { return __builtin_amdgcn_exp2f(x); }  // v_exp_f32 (base 2)

DEVI void gl_lds16(const void* g, void* l) {  // 16B/lane global->LDS DMA
  __builtin_amdgcn_global_load_lds(
      (__attribute__((address_space(1))) uint32_t*)g,
      (__attribute__((address_space(3))) uint32_t*)l, 16, 0, 0);
}

DEVI f32x4 mfma16(bf16x8 a, bf16x8 b, f32x4 c) {
  return __builtin_amdgcn_mfma_f32_16x16x32_bf16(a, b, c, 0, 0, 0);
}

// ---------- f32 -> bf16 convert ----------
__global__ void k_cvt(const float* __restrict__ in, u16* __restrict__ out, int n) {
  int i = (blockIdx.x * blockDim.x + threadIdx.x) * 4;
  if (i >= n) return;
  float4 v = *reinterpret_cast<const float4*>(in + i);
  ushort4 o;
  o.x = f2bf(v.x); o.y = f2bf(v.y); o.z = f2bf(v.z); o.w = f2bf(v.w);
  *reinterpret_cast<ushort4*>(out + i) = o;
}

// ---------- bf16 GEMM: C[m][n] = sum_k A[m][k]*B[n][k] ----------
// 128x128 tile, BK=32, 4 waves (2x2 of 64x64), m97 structure.
// MODE 1: f32 out + bias (proj). MODE 2: fused RoPE epilogue -> q_bf/k_bf/v_bf.
template<int MODE>
__global__ __launch_bounds__(256, 2) void k_gemm(
    const u16* __restrict__ A, const u16* __restrict__ Bw,
    float* __restrict__ Cout, const float* __restrict__ bias,
    u16* __restrict__ qb, u16* __restrict__ kb, u16* __restrict__ vb,
    int Nn, int K) {
  __shared__ u16 Al[128 * 32];
  __shared__ u16 Bl[128 * 32];
  const int tid = threadIdx.x, wid = tid >> 6, lane = tid & 63;
  const int bm = blockIdx.x, bn = blockIdx.y;
  const int wr = wid >> 1, wc = wid & 1;
  f32x4 acc[4][4] = {};

  const int r0 = wid * 16 + (lane >> 2);   // staging row within 64-row shot
  const int c0 = (lane & 3) * 8;           // staging k-offset (elems)
  const u16* Ag = A + (size_t)(bm * 128) * K + c0;
  const u16* Bg = Bw + (size_t)(bn * 128) * K + c0;
  u16* Alb = Al + wid * 512;               // wave-uniform LDS dst (bytes wid*1024)
  u16* Blb = Bl + wid * 512;
  const int fr = lane & 15, fk = (lane >> 4) * 8;

  for (int kt = 0; kt < K; kt += 32) {
    __syncthreads();
    gl_lds16(Ag + (size_t)r0 * K + kt,        Alb);
    gl_lds16(Ag + (size_t)(64 + r0) * K + kt, Alb + 2048);
    gl_lds16(Bg + (size_t)r0 * K + kt,        Blb);
    gl_lds16(Bg + (size_t)(64 + r0) * K + kt, Blb + 2048);
    __syncthreads();
    bf16x8 af[4], bfr[4];
#pragma unroll
    for (int i = 0; i < 4; ++i)
      af[i] = *reinterpret_cast<const bf16x8*>(&Al[(wr * 64 + i * 16 + fr) * 32 + fk]);
#pragma unroll
    for (int j = 0; j < 4; ++j)
      bfr[j] = *reinterpret_cast<const bf16x8*>(&Bl[(wc * 64 + j * 16 + fr) * 32 + fk]);
#pragma unroll
    for (int i = 0; i < 4; ++i)
#pragma unroll
      for (int j = 0; j < 4; ++j)
        acc[i][j] = mfma16(af[i], bfr[j], acc[i][j]);
  }
  // D frag layout: row=(lane>>4)*4+r (M), col=lane&15 (N)  [m89-verified]
  const int orow0 = bm * 128 + wr * 64 + (lane >> 4) * 4;

  if constexpr (MODE == 1) {
    const int ocol0 = bn * 128 + wc * 64 + fr;
#pragma unroll
    for (int j = 0; j < 4; ++j) {
      int col = ocol0 + j * 16;
      float badd = bias[col];
#pragma unroll
      for (int i = 0; i < 4; ++i)
#pragma unroll
        for (int r = 0; r < 4; ++r)
          Cout[(size_t)(orow0 + i * 16 + r) * Nn + col] = acc[i][j][r] + badd;
    }
  } else {  // MODE == 2: fused RoPE. Block is purely q / k / v: which = bn>>3.
    const int which = bn >> 3;
    const int cbase = (bn & 7) * 128 + wc * 64 + fr;   // col within this 1024-block
    u16* dst = (which == 0) ? qb : (which == 1) ? kb : vb;
#pragma unroll
    for (int j = 0; j < 4; ++j) {
      const int c = cbase + j * 16;
      const int d = c & 63, hh = c >> 6;
      const bool dorope = (which != 2) && (d < 60);
      int seg = 0; float omega = 0.f;
      if (dorope) {
        seg = d / 20;
        int ds = d - seg * 20;
        int jj = (ds >= 10) ? ds - 10 : ds;
        omega = exp2fast(-1.3287712379549449f * (float)jj);  // 10000^(-jj/10)
      }
#pragma unroll
      for (int i = 0; i < 4; ++i) {
#pragma unroll
        for (int r = 0; r < 4; ++r) {
          const int m = orow0 + i * 16 + r;
          const int b = m >> 11, n = m & (NTOK - 1);
          float val = acc[i][j][r];
          float pr = __shfl_xor(val, 1, 64);   // RoPE pair partner (col c^1)
          float outv = val;
          if (dorope) {
            float pos = (seg == 0) ? (float)(n >> 8)
                      : (seg == 1) ? (float)((n >> 4) & 15)
                                   : (float)(n & 15);
            float f = pos * omega, sn, cs;
            __sincosf(f, &sn, &cs);
            outv = (d & 1) ? val * cs + pr * sn : val * cs - pr * sn;
          }
          if (which == 0) outv *= 0.18033688011112042f;  // 0.125 * log2(e)
          dst[((size_t)(b * 16 + hh) * NTOK + n) * 64 + d] = f2bf(outv);
        }
      }
    }
  }
}

// ---------- V transpose: v_bf [bh][n][d] -> vT [bh][d][n], bf16 ----------
__global__ void k_vt(const u16* __restrict__ vb, u16* __restrict__ vT) {
  __shared__ u16 tile[64][72];
  const int bh = blockIdx.x;
  const int n0 = blockIdx.y * 64;
  const int t = threadIdx.x;
  const int nr = t >> 2, cq = (t & 3) * 16;
  const u16* src = vb + ((size_t)bh * NTOK + n0 + nr) * 64 + cq;
  *reinterpret_cast<bf16x8*>(&tile[nr][cq])     = *reinterpret_cast<const bf16x8*>(src);
  *reinterpret_cast<bf16x8*>(&tile[nr][cq + 8]) = *reinterpret_cast<const bf16x8*>(src + 8);
  __syncthreads();
  const int d = t >> 2, nq = (t & 3) * 16;
  u16 buf[16];
#pragma unroll
  for (int i = 0; i < 16; ++i) buf[i] = tile[nq + i][d];
  u16* dst = vT + ((size_t)bh * 64 + d) * NTOK + n0 + nq;
  *reinterpret_cast<bf16x8*>(dst)     = *reinterpret_cast<const bf16x8*>(&buf[0]);
  *reinterpret_cast<bf16x8*>(dst + 8) = *reinterpret_cast<const bf16x8*>(&buf[8]);
}

// ---------- flash attention ----------
// 4 waves/block; wave w owns 32 q-rows (2 x 16-row frags); KVBLK=64, dbuf LDS.
// All LDS tiles XOR-swizzled: 16B-chunk index ^= (row & 7); global_load_lds
// linear-dest with pre-swizzled GLOBAL source (rule #21).
// S^T = mfma(K,Q): lane holds S^T[kv=mf*16+fg*4+r][q=fr].
__global__ __launch_bounds__(256, 2) void k_attn(
    const u16* __restrict__ qb, const u16* __restrict__ kb,
    const u16* __restrict__ vT, u16* __restrict__ outb) {
  __shared__ u16 Kl[2][64 * 64];   // [kv][d]   rows 128B, swizzled
  __shared__ u16 Vl[2][64 * 64];   // [d][kv]   rows 128B, swizzled
  __shared__ u16 Pl[4][32 * 64];   // per-wave P [q][kv], rows 128B, swizzled
  const int bh = blockIdx.x;       // b*16+h
  const int qt = blockIdx.y;       // q-tile (128 rows)
  const int tid = threadIdx.x, wid = tid >> 6, lane = tid & 63;
  const int fr = lane & 15, fg = lane >> 4;
  const int swz = fr & 7;

  bf16x8 qf[2][2];
  const u16* qbase = qb + ((size_t)bh * NTOK + qt * 128 + wid * 32 + fr) * 64;
#pragma unroll
  for (int qa = 0; qa < 2; ++qa)
#pragma unroll
    for (int h = 0; h < 2; ++h)
      qf[qa][h] = *reinterpret_cast<const bf16x8*>(qbase + qa * 1024 + h * 32 + fg * 8);

  f32x4 acc[2][4] = {};
  float mrun[2] = {-1e30f, -1e30f}, lrun[2] = {0.f, 0.f};

  const int srow = lane >> 3;                 // 0..7
  const int scol = ((lane & 7) ^ srow) * 8;   // pre-swizzled source col (elems)
  const u16* kg = kb + ((size_t)bh * NTOK + wid * 8 + srow) * 64 + scol;
  const u16* vg = vT + ((size_t)bh * 64 + wid * 8 + srow) * NTOK + scol;
  u16* Pw = &Pl[wid][0];

  auto stage = [&](int buf, int kvt) {
#pragma unroll
    for (int s = 0; s < 2; ++s) {
      gl_lds16(kg + (size_t)(kvt + s * 32) * 64, &Kl[buf][s * 2048 + wid * 512]);
      gl_lds16(vg + (size_t)(s * 32) * NTOK + kvt, &Vl[buf][s * 2048 + wid * 512]);
    }
  };

  stage(0, 0);
  __syncthreads();
  int cur = 0;
  for (int kvt = 0; kvt < NTOK; kvt += 64) {
    if (kvt + 64 < NTOK) stage(cur ^ 1, kvt + 64);
    const u16* Kc = &Kl[cur][0];
    const u16* Vc = &Vl[cur][0];

    bf16x8 kf[4][2], vf[4][2];
#pragma unroll
    for (int mf = 0; mf < 4; ++mf) {
      int rb = (mf * 16 + fr) * 64;
#pragma unroll
      for (int h = 0; h < 2; ++h)
        kf[mf][h] = *reinterpret_cast<const bf16x8*>(Kc + rb + (((h * 4 + fg) ^ swz) * 8));
    }
#pragma unroll
    for (int nf = 0; nf < 4; ++nf) {
      int rb = (nf * 16 + fr) * 64;
#pragma unroll
      for (int ks = 0; ks < 2; ++ks)
        vf[nf][ks] = *reinterpret_cast<const bf16x8*>(Vc + rb + (((ks * 4 + fg) ^ swz) * 8));
    }

    // QK^T
    f32x4 st[2][4];
    __builtin_amdgcn_s_setprio(1);
#pragma unroll
    for (int qa = 0; qa < 2; ++qa)
#pragma unroll
      for (int mf = 0; mf < 4; ++mf) {
        f32x4 s0 = {};
        s0 = mfma16(kf[mf][0], qf[qa][0], s0);
        s0 = mfma16(kf[mf][1], qf[qa][1], s0);
        st[qa][mf] = s0;
      }
    __builtin_amdgcn_s_setprio(0);

    // online softmax (log2 domain; scale folded into q), defer-max THR=8
    float corrA[2]; bool skipA[2];
#pragma unroll
    for (int qa = 0; qa < 2; ++qa) {
      float t0 = fmaxf(fmaxf(st[qa][0][0], st[qa][0][1]), fmaxf(st[qa][0][2], st[qa][0][3]));
      float t1 = fmaxf(fmaxf(st[qa][1][0], st[qa][1][1]), fmaxf(st[qa][1][2], st[qa][1][3]));
      float t2 = fmaxf(fmaxf(st[qa][2][0], st[qa][2][1]), fmaxf(st[qa][2][2], st[qa][2][3]));
      float t3 = fmaxf(fmaxf(st[qa][3][0], st[qa][3][1]), fmaxf(st[qa][3][2], st[qa][3][3]));
      float tm = fmaxf(fmaxf(t0, t1), fmaxf(t2, t3));
      tm = fmaxf(tm, __shfl_xor(tm, 16, 64));
      tm = fmaxf(tm, __shfl_xor(tm, 32, 64));
      skipA[qa] = (__all(tm - mrun[qa] <= 8.f) != 0);
      float mref;
      if (skipA[qa]) {
        corrA[qa] = 1.f; mref = mrun[qa];
      } else {
        float mnew = fmaxf(mrun[qa], tm);
        corrA[qa] = exp2fast(mrun[qa] - mnew);
        mrun[qa] = mnew; mref = mnew;
      }
      float ps = 0.f;
      const int prow = qa * 16 + fr;
#pragma unroll
      for (int mf = 0; mf < 4; ++mf) {
        float p0 = exp2fast(st[qa][mf][0] - mref);
        float p1 = exp2fast(st[qa][mf][1] - mref);
        float p2 = exp2fast(st[qa][mf][2] - mref);
        float p3 = exp2fast(st[qa][mf][3] - mref);
        ps += (p0 + p1) + (p2 + p3);
        uint32_t k0, k1;
        asm("v_cvt_pk_bf16_f32 %0, %1, %2" : "=v"(k0) : "v"(p0), "v"(p1));
        asm("v_cvt_pk_bf16_f32 %0, %1, %2" : "=v"(k1) : "v"(p2), "v"(p3));
        int c16 = (mf * 2 + (fg >> 1)) ^ swz;
        uint2 val; val.x = k0; val.y = k1;
        *reinterpret_cast<uint2*>(Pw + prow * 64 + c16 * 8 + (fg & 1) * 4) = val;
      }
      ps += __shfl_xor(ps, 16, 64);
      ps += __shfl_xor(ps, 32, 64);
      lrun[qa] = lrun[qa] * corrA[qa] + ps;
    }

    // rule-18 fence: P writes must land before P fragment re-read
    __builtin_amdgcn_sched_barrier(0);
    asm volatile("s_waitcnt lgkmcnt(0)" ::: "memory");
    __builtin_amdgcn_sched_barrier(0);

    // rescale (skipped when max deferred) + PV
#pragma unroll
    for (int qa = 0; qa < 2; ++qa) {
      if (!skipA[qa]) {
        float cr[4];
#pragma unroll
        for (int r = 0; r < 4; ++r) cr[r] = __shfl(corrA[qa], fg * 4 + r, 64);
#pragma unroll
        for (int nf = 0; nf < 4; ++nf)
#pragma unroll
          for (int r = 0; r < 4; ++r) acc[qa][nf][r] *= cr[r];
      }
      const int prow = qa * 16 + fr;
      bf16x8 pa[2];
#pragma unroll
      for (int ks = 0; ks < 2; ++ks)
        pa[ks] = *reinterpret_cast<const bf16x8*>(Pw + prow * 64 + (((ks * 4 + fg) ^ swz) * 8));
      __builtin_amdgcn_s_setprio(1);
#pragma unroll
      for (int nf = 0; nf < 4; ++nf)
#pragma unroll
        for (int ks = 0; ks < 2; ++ks)
          acc[qa][nf] = mfma16(pa[ks], vf[nf][ks], acc[qa][nf]);
      __builtin_amdgcn_s_setprio(0);
    }
    __syncthreads();
    cur ^= 1;
  }

  // normalize + write [b][n][h*64+d] bf16
  const int b = bh >> 4, h = bh & 15;
#pragma unroll
  for (int qa = 0; qa < 2; ++qa) {
    float linv[4];
#pragma unroll
    for (int r = 0; r < 4; ++r) linv[r] = 1.f / __shfl(lrun[qa], fg * 4 + r, 64);
#pragma unroll
    for (int nf = 0; nf < 4; ++nf)
#pragma unroll
      for (int r = 0; r < 4; ++r) {
        int n = qt * 128 + wid * 32 + qa * 16 + fg * 4 + r;
        int col = h * 64 + nf * 16 + fr;
        outb[((size_t)b * NTOK + n) * CDIM + col] = f2bf(acc[qa][nf][r] * linv[r]);
      }
  }
}

// ---------- launcher ----------
extern "C" void kernel_launch(void* const* d_in, const int* in_sizes, int n_in,
                              void* d_out, int out_size, void* d_ws, size_t ws_size,
                              hipStream_t stream) {
  (void)in_sizes; (void)n_in; (void)out_size; (void)ws_size;
  const float* x  = (const float*)d_in[0];
  const float* Wq = (const float*)d_in[1];
  const float* Wp = (const float*)d_in[2];
  const float* bp = (const float*)d_in[3];
  // T=8, H=16, W=16 fixed (d_in[4..6]); N = 2048 = T*H*W.

  char* w = (char*)d_ws;
  u16* x_bf  = (u16*)(w + 0);          //  8,388,608 B
  u16* wq_bf = (u16*)(w + 8388608);    //  6,291,456
  u16* wp_bf = (u16*)(w + 14680064);   //  2,097,152
  u16* q_bf  = (u16*)(w + 16777216);   //  8,388,608
  u16* k_bf  = (u16*)(w + 25165824);   //  8,388,608
  u16* v_bf  = (u16*)(w + 33554432);   //  8,388,608
  u16* vT    = (u16*)(w + 41943040);   //  8,388,608
  u16* at_bf = (u16*)(w + 50331648);   //  8,388,608  (total ~58.7 MB)

  k_cvt<<<4096, 256, 0, stream>>>(x,  x_bf,  4194304);
  k_cvt<<<3072, 256, 0, stream>>>(Wq, wq_bf, 3145728);
  k_cvt<<<1024, 256, 0, stream>>>(Wp, wp_bf, 1048576);

  // QKV GEMM with fused RoPE epilogue -> q_bf / k_bf / v_bf (bf16)
  k_gemm<2><<<dim3(32, 24), 256, 0, stream>>>(x_bf, wq_bf, nullptr, nullptr,
                                              q_bf, k_bf, v_bf, C3, CDIM);

  k_vt<<<dim3(32, 32), 256, 0, stream>>>(v_bf, vT);

  k_attn<<<dim3(32, 16), 256, 0, stream>>>(q_bf, k_bf, vT, at_bf);

  k_gemm<1><<<dim3(32, 8), 256, 0, stream>>>(at_bf, wp_bf, (float*)d_out, bp,
                                             nullptr, nullptr, nullptr, CDIM, CDIM);
}

// Round 5
// 128.278 us; speedup vs baseline: 1.7288x; 1.1025x over previous
//
#include <hip/hip_runtime.h>
#include <stdint.h>

typedef unsigned short u16;
typedef __attribute__((ext_vector_type(8))) short bf16x8;
typedef __attribute__((ext_vector_type(4))) float f32x4;

#define DEVI static __device__ __forceinline__

static constexpr int NTOK = 2048;   // N tokens (= T*H*W = 8*16*16)
static constexpr int CDIM = 1024;
static constexpr int C3   = 3072;

// ---------- helpers ----------
DEVI u16 f2bf(float f) {            // f32 -> bf16 bits, RNE
  uint32_t u = __float_as_uint(f);
  return (u16)((u + 0x7fffu + ((u >> 16) & 1u)) >> 16);
}

DEVI float exp2fast(float x) { return __builtin_amdgcn_exp2f(x); }  // v_exp_f32 (base 2)

DEVI void gl_lds16(const void* g, void* l) {  // 16B/lane global->LDS DMA
  __builtin_amdgcn_global_load_lds(
      (__attribute__((address_space(1))) uint32_t*)g,
      (__attribute__((address_space(3))) uint32_t*)l, 16, 0, 0);
}

DEVI f32x4 mfma16(bf16x8 a, bf16x8 b, f32x4 c) {
  return __builtin_amdgcn_mfma_f32_16x16x32_bf16(a, b, c, 0, 0, 0);
}

// ---------- f32 -> bf16 convert (x, W_qkv, W_proj in one launch) ----------
__global__ void k_cvt3(const float* __restrict__ x, const float* __restrict__ wq,
                       const float* __restrict__ wp, u16* __restrict__ xb,
                       u16* __restrict__ wqb, u16* __restrict__ wpb) {
  int i = (blockIdx.x * blockDim.x + threadIdx.x) * 4;   // over 8,388,608 elems
  const float* src; u16* dst; int off;
  if (i < 4194304)      { src = x;  dst = xb;  off = i; }
  else if (i < 7340032) { src = wq; dst = wqb; off = i - 4194304; }
  else                  { src = wp; dst = wpb; off = i - 7340032; }
  float4 v = *reinterpret_cast<const float4*>(src + off);
  ushort4 o;
  o.x = f2bf(v.x); o.y = f2bf(v.y); o.z = f2bf(v.z); o.w = f2bf(v.w);
  *reinterpret_cast<ushort4*>(dst + off) = o;
}

// ---------- bf16 GEMM: C[m][n] = sum_k A[m][k]*B[n][k] ----------
// 128x128 tile, BK=32, 4 waves (2x2 of 64x64), m97 structure.
// MODE 1: f32 out + bias (proj).
// MODE 2: fused RoPE epilogue -> q_bf/k_bf; v-blocks transposed into vT.
template<int MODE>
__global__ __launch_bounds__(256, 2) void k_gemm(
    const u16* __restrict__ A, const u16* __restrict__ Bw,
    float* __restrict__ Cout, const float* __restrict__ bias,
    u16* __restrict__ qb, u16* __restrict__ kb, u16* __restrict__ vT,
    int Nn, int K) {
  __shared__ u16 smem[MODE == 2 ? 17408 : 8192];   // loop: Al(4096)+Bl(4096); MODE2 epi: [128][136]
  u16* Al = smem;
  u16* Bl = smem + 4096;
  const int tid = threadIdx.x, wid = tid >> 6, lane = tid & 63;
  const int bm = blockIdx.x, bn = blockIdx.y;
  const int wr = wid >> 1, wc = wid & 1;
  const int fr = lane & 15, fg = lane >> 4;
  f32x4 acc[4][4] = {};

  const int r0 = wid * 16 + (lane >> 2);   // staging row within 64-row shot
  const int c0 = (lane & 3) * 8;           // staging k-offset (elems)
  const u16* Ag = A + (size_t)(bm * 128) * K + c0;
  const u16* Bg = Bw + (size_t)(bn * 128) * K + c0;
  u16* Alb = Al + wid * 512;               // wave-uniform LDS dst (bytes wid*1024)
  u16* Blb = Bl + wid * 512;
  const int fk = fg * 8;

  for (int kt = 0; kt < K; kt += 32) {
    __syncthreads();
    gl_lds16(Ag + (size_t)r0 * K + kt,        Alb);
    gl_lds16(Ag + (size_t)(64 + r0) * K + kt, Alb + 2048);
    gl_lds16(Bg + (size_t)r0 * K + kt,        Blb);
    gl_lds16(Bg + (size_t)(64 + r0) * K + kt, Blb + 2048);
    __syncthreads();
    bf16x8 af[4], bfr[4];
#pragma unroll
    for (int i = 0; i < 4; ++i)
      af[i] = *reinterpret_cast<const bf16x8*>(&Al[(wr * 64 + i * 16 + fr) * 32 + fk]);
#pragma unroll
    for (int j = 0; j < 4; ++j)
      bfr[j] = *reinterpret_cast<const bf16x8*>(&Bl[(wc * 64 + j * 16 + fr) * 32 + fk]);
#pragma unroll
    for (int i = 0; i < 4; ++i)
#pragma unroll
      for (int j = 0; j < 4; ++j)
        acc[i][j] = mfma16(af[i], bfr[j], acc[i][j]);
  }
  // D frag layout: row=(lane>>4)*4+r (M), col=lane&15 (N)  [m89-verified]
  const int orow0 = bm * 128 + wr * 64 + fg * 4;

  if constexpr (MODE == 1) {
    const int ocol0 = bn * 128 + wc * 64 + fr;
#pragma unroll
    for (int j = 0; j < 4; ++j) {
      int col = ocol0 + j * 16;
      float badd = bias[col];
#pragma unroll
      for (int i = 0; i < 4; ++i)
#pragma unroll
        for (int r = 0; r < 4; ++r)
          Cout[(size_t)(orow0 + i * 16 + r) * Nn + col] = acc[i][j][r] + badd;
    }
  } else {  // MODE == 2
    const int which = bn >> 3;   // 0=q, 1=k, 2=v (block-uniform)
    if (which < 2) {             // fused RoPE -> qb / kb  [bh][n][d]
      const int cbase = (bn & 7) * 128 + wc * 64 + fr;
      u16* dst = (which == 0) ? qb : kb;
#pragma unroll
      for (int j = 0; j < 4; ++j) {
        const int c = cbase + j * 16;
        const int d = c & 63, hh = c >> 6;
        const bool dorope = (d < 60);
        int seg = 0; float omega = 0.f;
        if (dorope) {
          seg = d / 20;
          int ds = d - seg * 20;
          int jj = (ds >= 10) ? ds - 10 : ds;
          omega = exp2fast(-1.3287712379549449f * (float)jj);  // 10000^(-jj/10)
        }
#pragma unroll
        for (int i = 0; i < 4; ++i) {
#pragma unroll
          for (int r = 0; r < 4; ++r) {
            const int m = orow0 + i * 16 + r;
            const int b = m >> 11, n = m & (NTOK - 1);
            float val = acc[i][j][r];
            float pr = __shfl_xor(val, 1, 64);   // RoPE pair partner (col c^1)
            float outv = val;
            if (dorope) {
              float pos = (seg == 0) ? (float)(n >> 8)
                        : (seg == 1) ? (float)((n >> 4) & 15)
                                     : (float)(n & 15);
              float f = pos * omega, sn, cs;
              __sincosf(f, &sn, &cs);
              outv = (d & 1) ? val * cs + pr * sn : val * cs - pr * sn;
            }
            if (which == 0) outv *= 0.18033688011112042f;  // 0.125 * log2(e)
            dst[((size_t)(b * 16 + hh) * NTOK + n) * 64 + d] = f2bf(outv);
          }
        }
      }
    } else {                     // V: LDS re-transpose -> vT [bh][d][n]
      __syncthreads();           // all waves done with Al/Bl
      const int mbase = wr * 64 + fg * 4;
#pragma unroll
      for (int j = 0; j < 4; ++j) {
        const int crow = wc * 64 + j * 16 + fr;
#pragma unroll
        for (int i = 0; i < 4; ++i) {
          ushort4 pk;
          pk.x = f2bf(acc[i][j][0]); pk.y = f2bf(acc[i][j][1]);
          pk.z = f2bf(acc[i][j][2]); pk.w = f2bf(acc[i][j][3]);
          *reinterpret_cast<ushort4*>(&smem[crow * 136 + mbase + i * 16]) = pk;
        }
      }
      __syncthreads();
      const int c = tid >> 1, mh = (tid & 1) * 64;
      const int cfull = (bn & 7) * 128 + c;
      const int hh = cfull >> 6, d = cfull & 63;
      const int b = bm >> 4;
      u16* dst = vT + (((size_t)(b * 16 + hh)) * 64 + d) * NTOK + (bm & 15) * 128 + mh;
      const u16* srcl = &smem[c * 136 + mh];
#pragma unroll
      for (int s = 0; s < 8; ++s)
        *reinterpret_cast<bf16x8*>(dst + s * 8) = *reinterpret_cast<const bf16x8*>(srcl + s * 8);
    }
  }
}

// ---------- flash attention ----------
// 4 waves/block; wave w owns 32 q-rows (2 x 16-row frags); KVBLK=64, dbuf LDS.
// LDS tiles XOR-swizzled (16B-chunk ^= row&7); gl_lds linear-dest with
// pre-swizzled GLOBAL source (rule #21).
// S^T = mfma(K,Q): lane holds S^T[kv=mf*16+fg*4+r][q=fr].
// Per-qa interleave SM->PV so PV(qa0) MFMAs overlap SM(qa1) VALU.
__global__ __launch_bounds__(256, 2) void k_attn(
    const u16* __restrict__ qb, const u16* __restrict__ kb,
    const u16* __restrict__ vT, u16* __restrict__ outb) {
  __shared__ u16 Kl[2][64 * 64];   // [kv][d]   rows 128B, swizzled
  __shared__ u16 Vl[2][64 * 64];   // [d][kv]   rows 128B, swizzled
  __shared__ u16 Pl[4][32 * 64];   // per-wave P [q][kv], rows 128B, swizzled
  const int bh = blockIdx.x;       // b*16+h
  const int qt = blockIdx.y;       // q-tile (128 rows)
  const int tid = threadIdx.x, wid = tid >> 6, lane = tid & 63;
  const int fr = lane & 15, fg = lane >> 4;
  const int swz = fr & 7;

  bf16x8 qf[2][2];
  const u16* qbase = qb + ((size_t)bh * NTOK + qt * 128 + wid * 32 + fr) * 64;
#pragma unroll
  for (int qa = 0; qa < 2; ++qa)
#pragma unroll
    for (int h = 0; h < 2; ++h)
      qf[qa][h] = *reinterpret_cast<const bf16x8*>(qbase + qa * 1024 + h * 32 + fg * 8);

  f32x4 acc[2][4] = {};
  float mrun[2] = {-1e30f, -1e30f}, lrun[2] = {0.f, 0.f};

  const int srow = lane >> 3;                 // 0..7
  const int scol = ((lane & 7) ^ srow) * 8;   // pre-swizzled source col (elems)
  const u16* kg = kb + ((size_t)bh * NTOK + wid * 8 + srow) * 64 + scol;
  const u16* vg = vT + ((size_t)bh * 64 + wid * 8 + srow) * NTOK + scol;
  u16* Pw = &Pl[wid][0];

  auto stage = [&](int buf, int kvt) {
#pragma unroll
    for (int s = 0; s < 2; ++s) {
      gl_lds16(kg + (size_t)(kvt + s * 32) * 64, &Kl[buf][s * 2048 + wid * 512]);
      gl_lds16(vg + (size_t)(s * 32) * NTOK + kvt, &Vl[buf][s * 2048 + wid * 512]);
    }
  };

  stage(0, 0);
  __syncthreads();
  int cur = 0;
  for (int kvt = 0; kvt < NTOK; kvt += 64) {
    if (kvt + 64 < NTOK) stage(cur ^ 1, kvt + 64);
    const u16* Kc = &Kl[cur][0];
    const u16* Vc = &Vl[cur][0];

    bf16x8 kf[4][2], vf[4][2];
#pragma unroll
    for (int mf = 0; mf < 4; ++mf) {
      int rb = (mf * 16 + fr) * 64;
#pragma unroll
      for (int h = 0; h < 2; ++h)
        kf[mf][h] = *reinterpret_cast<const bf16x8*>(Kc + rb + (((h * 4 + fg) ^ swz) * 8));
    }
#pragma unroll
    for (int nf = 0; nf < 4; ++nf) {
      int rb = (nf * 16 + fr) * 64;
#pragma unroll
      for (int ks = 0; ks < 2; ++ks)
        vf[nf][ks] = *reinterpret_cast<const bf16x8*>(Vc + rb + (((ks * 4 + fg) ^ swz) * 8));
    }

    // QK^T for both q-frags
    f32x4 st[2][4];
    __builtin_amdgcn_s_setprio(1);
#pragma unroll
    for (int qa = 0; qa < 2; ++qa)
#pragma unroll
      for (int mf = 0; mf < 4; ++mf) {
        f32x4 s0 = {};
        s0 = mfma16(kf[mf][0], qf[qa][0], s0);
        s0 = mfma16(kf[mf][1], qf[qa][1], s0);
        st[qa][mf] = s0;
      }
    __builtin_amdgcn_s_setprio(0);

    // per-qa: softmax then PV (PV[0] MFMAs overlap SM[1] VALU)
#pragma unroll
    for (int qa = 0; qa < 2; ++qa) {
      float t0 = fmaxf(fmaxf(st[qa][0][0], st[qa][0][1]), fmaxf(st[qa][0][2], st[qa][0][3]));
      float t1 = fmaxf(fmaxf(st[qa][1][0], st[qa][1][1]), fmaxf(st[qa][1][2], st[qa][1][3]));
      float t2 = fmaxf(fmaxf(st[qa][2][0], st[qa][2][1]), fmaxf(st[qa][2][2], st[qa][2][3]));
      float t3 = fmaxf(fmaxf(st[qa][3][0], st[qa][3][1]), fmaxf(st[qa][3][2], st[qa][3][3]));
      float tm = fmaxf(fmaxf(t0, t1), fmaxf(t2, t3));
      tm = fmaxf(tm, __shfl_xor(tm, 16, 64));
      tm = fmaxf(tm, __shfl_xor(tm, 32, 64));
      bool skip = (__all(tm - mrun[qa] <= 8.f) != 0);
      float corr, mref;
      if (skip) {
        corr = 1.f; mref = mrun[qa];
      } else {
        float mnew = fmaxf(mrun[qa], tm);
        corr = exp2fast(mrun[qa] - mnew);
        mrun[qa] = mnew; mref = mnew;
      }
      float ps = 0.f;
      const int prow = qa * 16 + fr;
#pragma unroll
      for (int mf = 0; mf < 4; ++mf) {
        float p0 = exp2fast(st[qa][mf][0] - mref);
        float p1 = exp2fast(st[qa][mf][1] - mref);
        float p2 = exp2fast(st[qa][mf][2] - mref);
        float p3 = exp2fast(st[qa][mf][3] - mref);
        ps += (p0 + p1) + (p2 + p3);
        uint32_t k0, k1;
        asm("v_cvt_pk_bf16_f32 %0, %1, %2" : "=v"(k0) : "v"(p0), "v"(p1));
        asm("v_cvt_pk_bf16_f32 %0, %1, %2" : "=v"(k1) : "v"(p2), "v"(p3));
        int c16 = (mf * 2 + (fg >> 1)) ^ swz;
        uint2 val; val.x = k0; val.y = k1;
        *reinterpret_cast<uint2*>(Pw + prow * 64 + c16 * 8 + (fg & 1) * 4) = val;
      }
      ps += __shfl_xor(ps, 16, 64);
      ps += __shfl_xor(ps, 32, 64);
      lrun[qa] = lrun[qa] * corr + ps;

      asm volatile("" ::: "memory");   // compiler: keep P writes before P reads (HW DS is in-order per wave)

      if (!skip) {
        float cr[4];
#pragma unroll
        for (int r = 0; r < 4; ++r) cr[r] = __shfl(corr, fg * 4 + r, 64);
#pragma unroll
        for (int nf = 0; nf < 4; ++nf)
#pragma unroll
          for (int r = 0; r < 4; ++r) acc[qa][nf][r] *= cr[r];
      }
      bf16x8 pa[2];
#pragma unroll
      for (int ks = 0; ks < 2; ++ks)
        pa[ks] = *reinterpret_cast<const bf16x8*>(Pw + prow * 64 + (((ks * 4 + fg) ^ swz) * 8));
      __builtin_amdgcn_s_setprio(1);
#pragma unroll
      for (int nf = 0; nf < 4; ++nf)
#pragma unroll
        for (int ks = 0; ks < 2; ++ks)
          acc[qa][nf] = mfma16(pa[ks], vf[nf][ks], acc[qa][nf]);
      __builtin_amdgcn_s_setprio(0);
    }
    __syncthreads();
    cur ^= 1;
  }

  // normalize + write [b][n][h*64+d] bf16
  const int b = bh >> 4, h = bh & 15;
#pragma unroll
  for (int qa = 0; qa < 2; ++qa) {
    float linv[4];
#pragma unroll
    for (int r = 0; r < 4; ++r) linv[r] = 1.f / __shfl(lrun[qa], fg * 4 + r, 64);
#pragma unroll
    for (int nf = 0; nf < 4; ++nf)
#pragma unroll
      for (int r = 0; r < 4; ++r) {
        int n = qt * 128 + wid * 32 + qa * 16 + fg * 4 + r;
        int col = h * 64 + nf * 16 + fr;
        outb[((size_t)b * NTOK + n) * CDIM + col] = f2bf(acc[qa][nf][r] * linv[r]);
      }
  }
}

// ---------- launcher ----------
extern "C" void kernel_launch(void* const* d_in, const int* in_sizes, int n_in,
                              void* d_out, int out_size, void* d_ws, size_t ws_size,
                              hipStream_t stream) {
  (void)in_sizes; (void)n_in; (void)out_size; (void)ws_size;
  const float* x  = (const float*)d_in[0];
  const float* Wq = (const float*)d_in[1];
  const float* Wp = (const float*)d_in[2];
  const float* bp = (const float*)d_in[3];
  // T=8, H=16, W=16 fixed (d_in[4..6]); N = 2048 = T*H*W.

  char* w = (char*)d_ws;
  u16* x_bf  = (u16*)(w + 0);          //  8,388,608 B
  u16* wq_bf = (u16*)(w + 8388608);    //  6,291,456
  u16* wp_bf = (u16*)(w + 14680064);   //  2,097,152
  u16* q_bf  = (u16*)(w + 16777216);   //  8,388,608
  u16* k_bf  = (u16*)(w + 25165824);   //  8,388,608
  u16* vT    = (u16*)(w + 33554432);   //  8,388,608
  u16* at_bf = (u16*)(w + 41943040);   //  8,388,608  (total ~50 MB)

  k_cvt3<<<8192, 256, 0, stream>>>(x, Wq, Wp, x_bf, wq_bf, wp_bf);

  // QKV GEMM: fused RoPE -> q_bf/k_bf; v-blocks transposed -> vT
  k_gemm<2><<<dim3(32, 24), 256, 0, stream>>>(x_bf, wq_bf, nullptr, nullptr,
                                              q_bf, k_bf, vT, C3, CDIM);

  k_attn<<<dim3(32, 16), 256, 0, stream>>>(q_bf, k_bf, vT, at_bf);

  k_gemm<1><<<dim3(32, 8), 256, 0, stream>>>(at_bf, wp_bf, (float*)d_out, bp,
                                             nullptr, nullptr, nullptr, CDIM, CDIM);
}